// Round 14
// baseline (1206.752 us; speedup 1.0000x reference)
//
#include <hip/hip_runtime.h>

typedef unsigned short u16;
typedef __attribute__((ext_vector_type(4))) float   f32x4;
typedef __attribute__((ext_vector_type(8))) __bf16  bf16x8;
typedef __attribute__((ext_vector_type(4))) __bf16  bf16x4;
typedef __attribute__((ext_vector_type(8))) short   short8;
typedef __attribute__((ext_vector_type(4))) int     int32x4;
typedef __attribute__((ext_vector_type(4))) short   short4v;

#define MFMA16(a,b,c) __builtin_amdgcn_mfma_f32_16x16x32_bf16(a,b,c,0,0,0)

static __device__ __forceinline__ u16 f2bf(float f){
  unsigned u = __builtin_bit_cast(unsigned, f);
  return (u16)((u + 0x7fffu + ((u >> 16) & 1u)) >> 16);
}
static __device__ __forceinline__ float bf2f(u16 h){
  return __builtin_bit_cast(float, ((unsigned)h) << 16);
}
static __device__ __forceinline__ bf16x8 ldb16(const u16* p){
  return __builtin_bit_cast(bf16x8, *(const short8*)p);
}
static __device__ __forceinline__ void gload_lds16(const void* g, void* l){
  __builtin_amdgcn_global_load_lds(
      reinterpret_cast<const __attribute__((address_space(1))) unsigned int*>(
          reinterpret_cast<unsigned long long>(g)),
      reinterpret_cast<__attribute__((address_space(3))) unsigned int*>(
          reinterpret_cast<unsigned long long>(l)),
      16, 0, 0);
}

static constexpr int T_ = 1024, H_ = 4096, NH_ = 32, NKV_ = 8, I_ = 12288;

// ---------------- fused (optional add) + RMSNorm over H=4096, bf16 out ----------------
__global__ __launch_bounds__(256) void addnorm_kernel(
    const float* __restrict__ a, const float* __restrict__ b,
    const float* __restrict__ w, float* __restrict__ res_out,
    u16* __restrict__ x_out)
{
  const int t = blockIdx.x, tid = threadIdx.x;
  __shared__ float red[4];
  float vals[16]; float ss = 0.f;
  const size_t base = (size_t)t * H_;
  #pragma unroll
  for (int i = 0; i < 16; ++i){
    int c = tid + i*256;
    float v = a[base + c];
    if (b) v += b[base + c];
    vals[i] = v; ss += v*v;
  }
  #pragma unroll
  for (int off = 32; off; off >>= 1) ss += __shfl_xor(ss, off);
  if ((tid & 63) == 0) red[tid >> 6] = ss;
  __syncthreads();
  float tot = red[0] + red[1] + red[2] + red[3];
  float rn = rsqrtf(tot / (float)H_ + 1e-6f);
  #pragma unroll
  for (int i = 0; i < 16; ++i){
    int c = tid + i*256;
    if (res_out) res_out[base + c] = vals[i];
    x_out[base + c] = f2bf(vals[i] * rn * w[c]);
  }
}

// ---------------- fused split-K reduce + residual add + RMSNorm (o-proj path) ----------------
__global__ __launch_bounds__(256) void addnorm_red_kernel(
    const float* __restrict__ P, int nsplit,
    const float* __restrict__ resd, const float* __restrict__ w,
    float* __restrict__ res_out, u16* __restrict__ x_out)
{
  const int t = blockIdx.x, tid = threadIdx.x;
  __shared__ float red[4];
  float vals[16]; float ss = 0.f;
  const size_t base = (size_t)t * H_;
  const size_t stride = (size_t)T_ * H_;
  #pragma unroll
  for (int i = 0; i < 16; ++i){
    int c = tid + i*256;
    float v = resd[base + c];
    for (int z = 0; z < nsplit; ++z) v += P[(size_t)z*stride + base + c];
    vals[i] = v; ss += v*v;
  }
  #pragma unroll
  for (int off = 32; off; off >>= 1) ss += __shfl_xor(ss, off);
  if ((tid & 63) == 0) red[tid >> 6] = ss;
  __syncthreads();
  float tot = red[0] + red[1] + red[2] + red[3];
  float rn = rsqrtf(tot / (float)H_ + 1e-6f);
  #pragma unroll
  for (int i = 0; i < 16; ++i){
    int c = tid + i*256;
    res_out[base + c] = vals[i];
    x_out[base + c] = f2bf(vals[i] * rn * w[c]);
  }
}

// ---------------- R precompute: R[g][i][j] f32 -> Rt[g][j][i] bf16 (all 7 tensors) ----------------
__global__ __launch_bounds__(256) void rprep_kernel(
    const float* __restrict__ Rq, const float* __restrict__ Rk,
    const float* __restrict__ Rv, const float* __restrict__ Ro,
    const float* __restrict__ Rg_, const float* __restrict__ Ru,
    const float* __restrict__ Rd, u16* __restrict__ Rt)
{
  __shared__ float sR[128][129];
  const int b = blockIdx.x, tid = threadIdx.x;
  const float* src;
  if      (b <  32) src = Rq  + (size_t)(b      ) * 16384;
  else if (b <  64) src = Rk  + (size_t)(b -  32) * 16384;
  else if (b <  96) src = Rv  + (size_t)(b -  64) * 16384;
  else if (b < 128) src = Ro  + (size_t)(b -  96) * 16384;
  else if (b < 160) src = Rg_ + (size_t)(b - 128) * 16384;
  else if (b < 192) src = Ru  + (size_t)(b - 160) * 16384;
  else              src = Rd  + (size_t)(b - 192) * 16384;
  #pragma unroll
  for (int it = 0; it < 16; ++it){
    int idx = (it*256 + tid) * 4;
    float4 v = *(const float4*)&src[idx];
    int i = idx >> 7, j = idx & 127;
    sR[i][j] = v.x; sR[i][j+1] = v.y; sR[i][j+2] = v.z; sR[i][j+3] = v.w;
  }
  __syncthreads();
  u16* dst = Rt + (size_t)b * 16384;
  #pragma unroll
  for (int it = 0; it < 32; ++it){
    int idx = it*256 + tid;
    int j = idx >> 6, i2 = (idx & 63) * 2;
    unsigned lo = f2bf(sR[i2][j]), hi = f2bf(sR[i2+1][j]);
    *(unsigned*)&dst[j*128 + i2] = lo | (hi << 16);
  }
}

// ---------------- block-diagonal rotation, multi-tensor; optional fused silu(X)*X2 staging ----------------
__global__ __launch_bounds__(256) void rot_kernel(
    const u16* __restrict__ X, const u16* __restrict__ Rt,
    u16* __restrict__ Y0, u16* __restrict__ Y1, u16* __restrict__ Y2,
    int LD, int gpt, const u16* __restrict__ X2)
{
  __shared__ u16 sX[64][136];
  __shared__ u16 sRt[128][136];   // sRt[j][i]
  const int by = blockIdx.y, g = by % gpt;
  const int m0 = blockIdx.x * 64, tid = threadIdx.x;
  u16* Y = (by < gpt) ? Y0 : (by < 2*gpt ? Y1 : Y2);
  #pragma unroll
  for (int i = 0; i < 4; ++i){
    int vid = i*256 + tid, r = vid >> 4, c = (vid & 15) * 8;
    size_t gaddr = (size_t)(m0 + r) * LD + g*128 + c;
    short8 vx = *(const short8*)&X[gaddr];
    if (X2){
      short8 vu = *(const short8*)&X2[gaddr];
      const u16* px = (const u16*)&vx;
      const u16* pu = (const u16*)&vu;
      short8 o;
      u16* po = (u16*)&o;
      #pragma unroll
      for (int e = 0; e < 8; ++e){
        float gv = bf2f(px[e]), uv = bf2f(pu[e]);
        po[e] = f2bf(gv / (1.f + __expf(-gv)) * uv);
      }
      *(short8*)&sX[r][c] = o;
    } else {
      *(short8*)&sX[r][c] = vx;
    }
  }
  const u16* Rg = Rt + (size_t)by * 16384;
  #pragma unroll
  for (int it = 0; it < 8; ++it){
    int idx = it*256 + tid;
    int j = idx >> 4, c8 = (idx & 15) * 8;
    *(short8*)&sRt[j][c8] = *(const short8*)&Rg[j*128 + c8];
  }
  __syncthreads();
  const int lane = tid & 63, w = tid >> 6;
  const int fr = lane & 15, fq = lane >> 4, nw = w * 32;
  f32x4 acc[4][2];
  #pragma unroll
  for (int mi=0;mi<4;mi++)
    #pragma unroll
    for (int ni=0;ni<2;ni++) acc[mi][ni] = (f32x4){0.f,0.f,0.f,0.f};
  #pragma unroll
  for (int kk = 0; kk < 128; kk += 32){
    bf16x8 af[4], bv[2];
    #pragma unroll
    for (int mi=0;mi<4;mi++) af[mi] = ldb16(&sX[mi*16 + fr][kk + fq*8]);
    #pragma unroll
    for (int ni=0;ni<2;ni++) bv[ni] = ldb16(&sRt[nw + ni*16 + fr][kk + fq*8]);
    #pragma unroll
    for (int mi=0;mi<4;mi++)
      #pragma unroll
      for (int ni=0;ni<2;ni++)
        acc[mi][ni] = MFMA16(af[mi], bv[ni], acc[mi][ni]);
  }
  #pragma unroll
  for (int mi=0;mi<4;mi++)
    #pragma unroll
    for (int ni=0;ni<2;ni++)
      #pragma unroll
      for (int rg=0;rg<4;rg++){
        int m = m0 + mi*16 + fq*4 + rg;
        int n = g*128 + nw + ni*16 + fr;
        Y[(size_t)m * LD + n] = f2bf(acc[mi][ni][rg]);
      }
}

// ---------------- 128 x (NF*64) 8-wave GEMM, BK=32, fused int4 dequant ----------------
// 2 blocks/CU (LDS 48/40 KB). Wave-tile 64x64 (acc 4xNF f32x4 = 64 VGPR).
// Depth-1.5 schedule (single rB set), per K-tile(32):
//   { ADMA(t+1)[1] | 8 frag reads + 16 MFMA | vmcnt(1)->storeB (loadB(t+1) 1-tile cover) |
//     loadB(t+2)[2NF] | vmcnt(2NF) retires ADMA | lgkm0 | barrier }
template<int NF, bool PARTIAL, bool OUT_BF16>
__global__ __launch_bounds__(512) void gemm_deq(
    const u16* __restrict__ A, const int* __restrict__ QW,
    const float* __restrict__ SC, void* __restrict__ Cout,
    int N, int K, int kc, int nN)
{
  __shared__ u16 sA[2][4096];         // [128][32] bf16, 64B rows, byte^=(row&3)<<4
  __shared__ u16 sB[2][NF * 2048];    // [NF*64][32], same swizzle
  const int tid = threadIdx.x;
  const int lane = tid & 63, w = tid >> 6;
  const int nblk = gridDim.x, q8 = nblk >> 3, b = blockIdx.x;
  const int l = (b & 7) * q8 + (b >> 3);
  const int mt = l & 7, rest = l >> 3;
  const int nt = rest % nN, z = rest / nN;
  const int bm0 = mt * 128, bn0 = nt * (NF * 64);
  const int kbase = z * kc;
  const int KG = K >> 7;
  const int nkt = kc >> 5;

  f32x4 acc[4][NF];
  #pragma unroll
  for (int i=0;i<4;i++)
    #pragma unroll
    for (int j=0;j<NF;j++) acc[i][j] = (f32x4){0.f,0.f,0.f,0.f};

  const int wr = (w >> 2) * 64, wc = (w & 3) * (NF * 16);
  const int fr = lane & 15, fq = lane >> 4;

  // ---- A DMA: 1 inst/wave. lane: row w*16 + (lane>>2), byte (lane&3)*16 (pre-swizzled src)
  const int lr = lane >> 2;
  const char* gA0 = (const char*)A
      + ((size_t)(bm0 + w*16 + lr) * K + (size_t)kbase) * 2
      + (((lane & 3) * 16) ^ ((lr & 3) << 4));
  auto ADMA = [&](int kt, int c){
    gload_lds16(gA0 + (size_t)kt * 64, (char*)&sA[c][0] + w * 1024);
  };

  // ---- B staging: thread covers k-ints (tid&7)*4..+3, rows (tid>>3) + 64i (i<NF)
  const int rB0 = tid >> 3, cB = (tid & 7) * 4;
  const int* gB0 = QW + (size_t)(bn0 + rB0) * K + kbase + cB;
  const float* gS0 = SC + (size_t)(bn0 + rB0) * KG;
  const int sBx = (cB * 2) ^ ((rB0 & 3) << 4);   // (r&3) invariant under +64i

  int32x4 rB[NF];
  float   rS[NF];
  auto loadB = [&](int kt){
    const int* gb = gB0 + kt*32;
    const int g = (kbase + kt*32) >> 7;
    const float* ps = gS0 + g;
    #pragma unroll
    for (int i=0;i<NF;i++){
      rB[i] = *(const int32x4*)(gb + (size_t)i*64*K);
      rS[i] = ps[(size_t)i*64*KG];
    }
  };
  auto storeB = [&](int c){
    #pragma unroll
    for (int i=0;i<NF;i++){
      float s = rS[i], ns = -8.f * s;
      bf16x4 o;
      o[0] = (__bf16)fmaf((float)rB[i].x, s, ns);
      o[1] = (__bf16)fmaf((float)rB[i].y, s, ns);
      o[2] = (__bf16)fmaf((float)rB[i].z, s, ns);
      o[3] = (__bf16)fmaf((float)rB[i].w, s, ns);
      *(bf16x4*)((char*)&sB[c][0] + (rB0 + 64*i)*64 + sBx) = o;
    }
  };

  auto mfma_tile = [&](int c){
    bf16x8 af[4], bv[NF];
    #pragma unroll
    for (int mi=0;mi<4;mi++){
      int r = wr + mi*16 + fr;
      af[mi] = *(const bf16x8*)((const char*)&sA[c][0] + r*64 +
                ((fq*16) ^ ((r & 3) << 4)));
    }
    #pragma unroll
    for (int ni=0;ni<NF;ni++){
      int r = wc + ni*16 + fr;
      bv[ni] = *(const bf16x8*)((const char*)&sB[c][0] + r*64 +
                ((fq*16) ^ ((r & 3) << 4)));
    }
    __builtin_amdgcn_s_setprio(1);
    #pragma unroll
    for (int mi=0;mi<4;mi++)
      #pragma unroll
      for (int ni=0;ni<NF;ni++)
        acc[mi][ni] = MFMA16(af[mi], bv[ni], acc[mi][ni]);
    __builtin_amdgcn_s_setprio(0);
  };

#define WAIT_2NF() do { if (NF==3) asm volatile("s_waitcnt vmcnt(6)" ::: "memory"); \
                        else       asm volatile("s_waitcnt vmcnt(8)" ::: "memory"); } while(0)

  // ---- prologue: stage tile 0 into buffers [0]; loadB(1) left in flight ----
  loadB(0);                 // 2NF vmem
  ADMA(0, 0);               // 1 vmem
  asm volatile("s_waitcnt vmcnt(1)" ::: "memory");   // B(0)+scales retired
  __builtin_amdgcn_sched_barrier(0);
  storeB(0);
  if (nkt > 1){ loadB(1); __builtin_amdgcn_sched_barrier(0); }
  WAIT_2NF();                                        // retire ADMA(0); loadB(1) stays
  asm volatile("s_waitcnt lgkmcnt(0)" ::: "memory");
  __builtin_amdgcn_s_barrier();

  int cb = 0;
  for (int t = 0; t < nkt; ++t){
    const bool more  = (t + 1) < nkt;
    const bool more2 = (t + 2) < nkt;
    if (more){
      ADMA(t+1, cb ^ 1);
      __builtin_amdgcn_sched_barrier(0);
    }
    mfma_tile(cb);
    if (more){
      asm volatile("s_waitcnt vmcnt(1)" ::: "memory");  // loadB(t+1): 1-tile cover
      __builtin_amdgcn_sched_barrier(0);
      storeB(cb ^ 1);
      __builtin_amdgcn_sched_barrier(0);
      if (more2){
        loadB(t+2);
        __builtin_amdgcn_sched_barrier(0);
        WAIT_2NF();                     // retire ADMA(t+1); loadB(t+2) stays
      } else {
        asm volatile("s_waitcnt vmcnt(0)" ::: "memory");
      }
      asm volatile("s_waitcnt lgkmcnt(0)" ::: "memory");
      __builtin_amdgcn_sched_barrier(0);
      __builtin_amdgcn_s_barrier();
      cb ^= 1;
    }
  }
#undef WAIT_2NF

  #pragma unroll
  for (int mi=0;mi<4;mi++)
    #pragma unroll
    for (int ni=0;ni<NF;ni++)
      #pragma unroll
      for (int rg=0;rg<4;rg++){
        size_t m = bm0 + wr + mi*16 + fq*4 + rg;
        size_t n = bn0 + wc + ni*16 + fr;
        float v = acc[mi][ni][rg];
        if (PARTIAL)          ((float*)Cout)[((size_t)z*1024 + m) * N + n] = v;
        else if (OUT_BF16)    ((u16*)Cout)[m * N + n] = f2bf(v);
        else                  ((float*)Cout)[m * N + n] = v;
      }
}

// ---------------- split-K reduce (f32x4), optional addend, f32 or bf16 out ----------------
__global__ __launch_bounds__(256) void reduce_splits(
    const float* __restrict__ P, int nsplit, int n,
    const float* __restrict__ addend, float* __restrict__ outf, u16* __restrict__ outb)
{
  size_t base = ((size_t)blockIdx.x*256 + threadIdx.x) * 4;
  if (base >= (size_t)n) return;
  f32x4 s = *(const f32x4*)&P[base];
  for (int j = 1; j < nsplit; ++j)
    s += *(const f32x4*)&P[(size_t)j*n + base];
  if (addend) s += *(const f32x4*)&addend[base];
  if (outb){
    short4v o;
    #pragma unroll
    for (int e=0;e<4;e++) o[e] = (short)f2bf(s[e]);
    *(short4v*)&outb[base] = o;
  } else {
    *(f32x4*)&outf[base] = s;
  }
}

// ---------------- fused split-K reduce + per-(t,head) RMSNorm over D=128 + RoPE ----------------
__global__ __launch_bounds__(64) void qknorm_rope_red(
    const float* __restrict__ P, int nsplit, int nh,
    const float* __restrict__ w, const int* __restrict__ pos, u16* __restrict__ out)
{
  const int t = blockIdx.x, h = blockIdx.y, j = threadIdx.x;
  const int N = nh * 128;
  const size_t stride = (size_t)T_ * N;
  const size_t base = (size_t)t * N + h*128;
  float x1 = 0.f, x2 = 0.f;
  for (int z = 0; z < nsplit; ++z){
    x1 += P[(size_t)z*stride + base + j];
    x2 += P[(size_t)z*stride + base + j + 64];
  }
  float ss = x1*x1 + x2*x2;
  #pragma unroll
  for (int off = 32; off; off >>= 1) ss += __shfl_xor(ss, off);
  float rn = rsqrtf(ss / 128.f + 1e-6f);
  float xn1 = x1 * rn * w[j], xn2 = x2 * rn * w[j + 64];
  float inv = exp2f(-(float)j * (19.93156856932417f / 64.f));
  float f = (float)pos[t] * inv;
  float sv, cv; sincosf(f, &sv, &cv);
  u16* orow = out + ((size_t)t * nh + h) * 128;
  orow[j]      = f2bf(xn1 * cv - xn2 * sv);
  orow[j + 64] = f2bf(xn2 * cv + xn1 * sv);
}

// ---------------- causal GQA flash attention, D=128, KV tiles of 32 ----------------
__global__ __launch_bounds__(256) void attn_kernel(
    const u16* __restrict__ Q, const u16* __restrict__ Kc,
    const u16* __restrict__ Vc, u16* __restrict__ O)
{
  __shared__ u16 sK[32][136];
  __shared__ u16 sVt[128][40];
  __shared__ u16 sP[4][16][40];
  const int b = blockIdx.x;
  const int qt = (b < 256) ? (b & 15) : (15 - (b & 15));
  const int h = b >> 4;
  const int kvh = h >> 2;
  const int tid = threadIdx.x, lane = tid & 63, w = tid >> 6;
  const int fr = lane & 15, fq = lane >> 4;
  const int r0 = qt*64 + w*16;
  const float scale = 0.08838834764831845f;
  bf16x8 aq[4];
  #pragma unroll
  for (int kd=0;kd<4;kd++)
    aq[kd] = ldb16(&Q[(size_t)(r0 + fr) * 4096 + h*128 + kd*32 + fq*8]);
  f32x4 accO[8];
  #pragma unroll
  for (int ni=0;ni<8;ni++) accO[ni] = (f32x4){0.f,0.f,0.f,0.f};
  float mrow[4] = {-1e30f,-1e30f,-1e30f,-1e30f};
  float lrow[4] = {0.f,0.f,0.f,0.f};
  const int ntiles = (qt + 1) * 2;
  for (int jt = 0; jt < ntiles; ++jt){
    __syncthreads();
    #pragma unroll
    for (int i=0;i<2;i++){
      int vid = i*256 + tid, r = vid >> 4, c = (vid & 15) * 8;
      *(short8*)&sK[r][c] = *(const short8*)&Kc[(size_t)(jt*32 + r) * 1024 + kvh*128 + c];
      short8 vv = *(const short8*)&Vc[(size_t)(jt*32 + r) * 1024 + kvh*128 + c];
      const u16* pv = (const u16*)&vv;
      #pragma unroll
      for (int e=0;e<8;e++) sVt[c + e][r] = pv[e];
    }
    __syncthreads();
    f32x4 accS[2]; accS[0] = (f32x4){0.f,0.f,0.f,0.f}; accS[1] = accS[0];
    #pragma unroll
    for (int kd=0;kd<4;kd++){
      #pragma unroll
      for (int ni=0;ni<2;ni++){
        bf16x8 bk = ldb16(&sK[ni*16 + fr][kd*32 + fq*8]);
        accS[ni] = MFMA16(aq[kd], bk, accS[ni]);
      }
    }
    float s[2][4];
    #pragma unroll
    for (int ni=0;ni<2;ni++)
      #pragma unroll
      for (int rg=0;rg<4;rg++){
        int row = r0 + fq*4 + rg, col = jt*32 + ni*16 + fr;
        float v = accS[ni][rg] * scale;
        s[ni][rg] = (col <= row) ? v : -1e30f;
      }
    float alpha[4];
    #pragma unroll
    for (int rg=0;rg<4;rg++){
      float mx = fmaxf(s[0][rg], s[1][rg]);
      #pragma unroll
      for (int off=1; off<16; off<<=1) mx = fmaxf(mx, __shfl_xor(mx, off, 16));
      float mnew = fmaxf(mrow[rg], mx);
      alpha[rg] = __expf(mrow[rg] - mnew);
      mrow[rg] = mnew;
      float p0 = __expf(s[0][rg] - mnew), p1 = __expf(s[1][rg] - mnew);
      s[0][rg] = p0; s[1][rg] = p1;
      float ps = p0 + p1;
      #pragma unroll
      for (int off=1; off<16; off<<=1) ps += __shfl_xor(ps, off, 16);
      lrow[rg] = lrow[rg] * alpha[rg] + ps;
    }
    #pragma unroll
    for (int ni=0;ni<2;ni++)
      #pragma unroll
      for (int rg=0;rg<4;rg++)
        sP[w][fq*4 + rg][ni*16 + fr] = f2bf(s[ni][rg]);
    __syncthreads();
    #pragma unroll
    for (int ni=0;ni<8;ni++)
      #pragma unroll
      for (int rg=0;rg<4;rg++) accO[ni][rg] *= alpha[rg];
    bf16x8 ap = ldb16(&sP[w][fr][fq*8]);
    #pragma unroll
    for (int ni=0;ni<8;ni++){
      bf16x8 bv = ldb16(&sVt[ni*16 + fr][fq*8]);
      accO[ni] = MFMA16(ap, bv, accO[ni]);
    }
  }
  #pragma unroll
  for (int ni=0;ni<8;ni++)
    #pragma unroll
    for (int rg=0;rg<4;rg++){
      int row = r0 + fq*4 + rg, col = h*128 + ni*16 + fr;
      O[(size_t)row * 4096 + col] = f2bf(accO[ni][rg] / lrow[rg]);
    }
}

extern "C" void kernel_launch(void* const* d_in, const int* in_sizes, int n_in,
                              void* d_out, int out_size, void* d_ws, size_t ws_size,
                              hipStream_t stream)
{
  const int*   positions = (const int*)  d_in[0];
  const float* hs    = (const float*)d_in[1];
  const float* resid = (const float*)d_in[2];
  const float* w_in  = (const float*)d_in[3];
  const float* w_post= (const float*)d_in[4];
  const float* w_qn  = (const float*)d_in[5];
  const float* w_kn  = (const float*)d_in[6];
  const float* R_q = (const float*)d_in[7];
  const int*   qw_q= (const int*)  d_in[8];
  const float* sc_q= (const float*)d_in[9];
  const float* R_k = (const float*)d_in[10];
  const int*   qw_k= (const int*)  d_in[11];
  const float* sc_k= (const float*)d_in[12];
  const float* R_v = (const float*)d_in[13];
  const int*   qw_v= (const int*)  d_in[14];
  const float* sc_v= (const float*)d_in[15];
  const float* R_o = (const float*)d_in[16];
  const int*   qw_o= (const int*)  d_in[17];
  const float* sc_o= (const float*)d_in[18];
  const float* R_g = (const float*)d_in[19];
  const int*   qw_g= (const int*)  d_in[20];
  const float* sc_g= (const float*)d_in[21];
  const float* R_u = (const float*)d_in[22];
  const int*   qw_u= (const int*)  d_in[23];
  const float* sc_u= (const float*)d_in[24];
  const float* R_d = (const float*)d_in[25];
  const int*   qw_d= (const int*)  d_in[26];
  const float* sc_d= (const float*)d_in[27];
  (void)in_sizes; (void)n_in; (void)out_size; (void)ws_size;

  char* wsp = (char*)d_ws; size_t off = 0;
  auto alloc = [&](size_t bytes)->void*{
    void* p = wsp + off; off += (bytes + 255) & ~(size_t)255; return p;
  };
  float* res  = (float*)alloc((size_t)T_*H_*4);       // 16MB
  u16*   xbf  = (u16*)  alloc((size_t)T_*H_*2);       // 8MB
  u16*   xrA  = (u16*)  alloc((size_t)T_*H_*2);       // 8MB
  u16*   xrB  = (u16*)  alloc((size_t)T_*H_*2);       // 8MB
  u16*   xrC  = (u16*)  alloc((size_t)T_*H_*2);       // 8MB
  float* qf   = (float*)alloc((size_t)T_*4096*4);     // 16MB (scratch)
  float* kf   = (float*)alloc((size_t)T_*1024*4);     // 4MB  (scratch)
  u16*   qbf  = (u16*)  alloc((size_t)T_*4096*2);     // 8MB
  u16*   kbf  = (u16*)  alloc((size_t)T_*1024*2);     // 2MB
  u16*   vbf  = (u16*)  alloc((size_t)T_*1024*2);     // 2MB
  u16*   abf  = (u16*)  alloc((size_t)T_*4096*2);     // 8MB
  u16*   gbf  = (u16*)  alloc((size_t)T_*I_*2);       // 24MB
  u16*   ubf  = (u16*)  alloc((size_t)T_*I_*2);       // 24MB
  u16*   hbf  = (u16*)  alloc((size_t)T_*I_*2);       // 24MB
  u16*   Rtb  = (u16*)  alloc((size_t)288*16384*2);   // 9.4MB precomputed R^T bf16
  (void)qf; (void)kf;

  // split-K partial regions reuse dead buffers (all sequential on one stream):
  float* pQKV = (float*)gbf;   // gbf..hbf (72MB) dead until gate-GEMM (need <=64MB)
  float* pO   = (float*)gbf;
  float* pD   = (float*)wsp;   // res..qf (64MB) dead at down-proj

  float* h2   = (float*)d_out;
  float* res2 = (float*)d_out + (size_t)T_*H_;

  rprep_kernel<<<288, 256, 0, stream>>>(R_q, R_k, R_v, R_o, R_g, R_u, R_d, Rtb);
  addnorm_kernel<<<T_, 256, 0, stream>>>(hs, resid, w_in, res, xbf);
  // QKV rotations in one launch (share xbf)
  rot_kernel<<<dim3(16,96),256,0,stream>>>(xbf, Rtb, xrA, xrB, xrC, H_, 32, nullptr);
  // q: N=4096 nN=16, z=4 (kc=1024) -> 8*16*4 = 512 blocks (2/CU); fused reduce+norm+rope
  gemm_deq<4,true ,false><<<512,512,0,stream>>>(xrA, qw_q, sc_q, pQKV, 4096, 4096, 1024, 16);
  qknorm_rope_red<<<dim3(T_,NH_ ),64,0,stream>>>(pQKV, 4, NH_, w_qn, positions, qbf);
  // k: N=1024 nN=4, z=16 (kc=256) -> 8*4*16 = 512 blocks; fused reduce+norm+rope
  gemm_deq<4,true ,false><<<512,512,0,stream>>>(xrB, qw_k, sc_k, pQKV, 1024, 4096, 256, 4);
  qknorm_rope_red<<<dim3(T_,NKV_),64,0,stream>>>(pQKV, 16, NKV_, w_kn, positions, kbf);
  // v: z=16 -> 512 blocks, bf16 out via reduce
  gemm_deq<4,true ,false><<<512,512,0,stream>>>(xrC, qw_v, sc_v, pQKV, 1024, 4096, 256, 4);
  reduce_splits<<<(T_*1024)/1024,256,0,stream>>>(pQKV, 16, T_*1024, nullptr, nullptr, vbf);
  attn_kernel<<<512,256,0,stream>>>(qbf, kbf, vbf, abf);
  rot_kernel<<<dim3(16,32),256,0,stream>>>(abf, Rtb + (size_t)96*16384, xrA, nullptr, nullptr, H_, 32, nullptr);
  // o: z=4 -> 512 blocks; fused reduce + residual + post-norm
  gemm_deq<4,true ,false><<<512,512,0,stream>>>(xrA, qw_o, sc_o, pO, 4096, 4096, 1024, 16);
  addnorm_red_kernel<<<T_,256,0,stream>>>(pO, 4, res, w_post, res2, xbf);
  // gate/up rotations in one launch
  rot_kernel<<<dim3(16,64),256,0,stream>>>(xbf, Rtb + (size_t)128*16384, xrA, xrB, nullptr, H_, 32, nullptr);
  // gate: NF=3 (BN=192), nN=64 -> 8*64 = 512 blocks, z=1, direct bf16 out
  gemm_deq<3,false,true ><<<512,512,0,stream>>>(xrA, qw_g, sc_g, gbf, 12288, 4096, 4096, 64);
  // up: same, plain
  gemm_deq<3,false,true ><<<512,512,0,stream>>>(xrB, qw_u, sc_u, ubf, 12288, 4096, 4096, 64);
  // down-rot with fused silu(gate)*up staging: reads gbf+ubf, writes rotated hbf
  rot_kernel<<<dim3(16,96),256,0,stream>>>(gbf, Rtb + (size_t)192*16384, hbf, nullptr, nullptr, I_, 96, ubf);
  // down: N=4096 nN=16, K=12288, z=4 (kc=3072) -> 512 blocks
  gemm_deq<4,true ,false><<<512,512,0,stream>>>(hbf, qw_d, sc_d, pD, 4096, 12288, 3072, 16);
  reduce_splits<<<(T_*4096)/1024,256,0,stream>>>(pD, 4, T_*4096, nullptr, h2, nullptr);
}

// Round 15
// 807.602 us; speedup vs baseline: 1.4942x; 1.4942x over previous
//
#include <hip/hip_runtime.h>

typedef unsigned short u16;
typedef __attribute__((ext_vector_type(4))) float   f32x4;
typedef __attribute__((ext_vector_type(8))) __bf16  bf16x8;
typedef __attribute__((ext_vector_type(4))) __bf16  bf16x4;
typedef __attribute__((ext_vector_type(8))) short   short8;
typedef __attribute__((ext_vector_type(4))) int     int32x4;
typedef __attribute__((ext_vector_type(4))) short   short4v;

#define MFMA16(a,b,c) __builtin_amdgcn_mfma_f32_16x16x32_bf16(a,b,c,0,0,0)

static __device__ __forceinline__ u16 f2bf(float f){
  unsigned u = __builtin_bit_cast(unsigned, f);
  return (u16)((u + 0x7fffu + ((u >> 16) & 1u)) >> 16);
}
static __device__ __forceinline__ float bf2f(u16 h){
  return __builtin_bit_cast(float, ((unsigned)h) << 16);
}
static __device__ __forceinline__ bf16x8 ldb16(const u16* p){
  return __builtin_bit_cast(bf16x8, *(const short8*)p);
}
static __device__ __forceinline__ void gload_lds16(const void* g, void* l){
  __builtin_amdgcn_global_load_lds(
      reinterpret_cast<const __attribute__((address_space(1))) unsigned int*>(
          reinterpret_cast<unsigned long long>(g)),
      reinterpret_cast<__attribute__((address_space(3))) unsigned int*>(
          reinterpret_cast<unsigned long long>(l)),
      16, 0, 0);
}

static constexpr int T_ = 1024, H_ = 4096, NH_ = 32, NKV_ = 8, I_ = 12288;

// ---------------- fused (optional add) + RMSNorm over H=4096, bf16 out ----------------
__global__ __launch_bounds__(256) void addnorm_kernel(
    const float* __restrict__ a, const float* __restrict__ b,
    const float* __restrict__ w, float* __restrict__ res_out,
    u16* __restrict__ x_out)
{
  const int t = blockIdx.x, tid = threadIdx.x;
  __shared__ float red[4];
  float vals[16]; float ss = 0.f;
  const size_t base = (size_t)t * H_;
  #pragma unroll
  for (int i = 0; i < 16; ++i){
    int c = tid + i*256;
    float v = a[base + c];
    if (b) v += b[base + c];
    vals[i] = v; ss += v*v;
  }
  #pragma unroll
  for (int off = 32; off; off >>= 1) ss += __shfl_xor(ss, off);
  if ((tid & 63) == 0) red[tid >> 6] = ss;
  __syncthreads();
  float tot = red[0] + red[1] + red[2] + red[3];
  float rn = rsqrtf(tot / (float)H_ + 1e-6f);
  #pragma unroll
  for (int i = 0; i < 16; ++i){
    int c = tid + i*256;
    if (res_out) res_out[base + c] = vals[i];
    x_out[base + c] = f2bf(vals[i] * rn * w[c]);
  }
}

// ---------------- fused split-K reduce + residual add + RMSNorm (o-proj path) ----------------
__global__ __launch_bounds__(256) void addnorm_red_kernel(
    const float* __restrict__ P, int nsplit,
    const float* __restrict__ resd, const float* __restrict__ w,
    float* __restrict__ res_out, u16* __restrict__ x_out)
{
  const int t = blockIdx.x, tid = threadIdx.x;
  __shared__ float red[4];
  float vals[16]; float ss = 0.f;
  const size_t base = (size_t)t * H_;
  const size_t stride = (size_t)T_ * H_;
  #pragma unroll
  for (int i = 0; i < 16; ++i){
    int c = tid + i*256;
    float v = resd[base + c];
    for (int z = 0; z < nsplit; ++z) v += P[(size_t)z*stride + base + c];
    vals[i] = v; ss += v*v;
  }
  #pragma unroll
  for (int off = 32; off; off >>= 1) ss += __shfl_xor(ss, off);
  if ((tid & 63) == 0) red[tid >> 6] = ss;
  __syncthreads();
  float tot = red[0] + red[1] + red[2] + red[3];
  float rn = rsqrtf(tot / (float)H_ + 1e-6f);
  #pragma unroll
  for (int i = 0; i < 16; ++i){
    int c = tid + i*256;
    res_out[base + c] = vals[i];
    x_out[base + c] = f2bf(vals[i] * rn * w[c]);
  }
}

// ---------------- R precompute: R[g][i][j] f32 -> Rt[g][j][i] bf16 (all 7 tensors) ----------------
__global__ __launch_bounds__(256) void rprep_kernel(
    const float* __restrict__ Rq, const float* __restrict__ Rk,
    const float* __restrict__ Rv, const float* __restrict__ Ro,
    const float* __restrict__ Rg_, const float* __restrict__ Ru,
    const float* __restrict__ Rd, u16* __restrict__ Rt)
{
  __shared__ float sR[128][129];
  const int b = blockIdx.x, tid = threadIdx.x;
  const float* src;
  if      (b <  32) src = Rq  + (size_t)(b      ) * 16384;
  else if (b <  64) src = Rk  + (size_t)(b -  32) * 16384;
  else if (b <  96) src = Rv  + (size_t)(b -  64) * 16384;
  else if (b < 128) src = Ro  + (size_t)(b -  96) * 16384;
  else if (b < 160) src = Rg_ + (size_t)(b - 128) * 16384;
  else if (b < 192) src = Ru  + (size_t)(b - 160) * 16384;
  else              src = Rd  + (size_t)(b - 192) * 16384;
  #pragma unroll
  for (int it = 0; it < 16; ++it){
    int idx = (it*256 + tid) * 4;
    float4 v = *(const float4*)&src[idx];
    int i = idx >> 7, j = idx & 127;
    sR[i][j] = v.x; sR[i][j+1] = v.y; sR[i][j+2] = v.z; sR[i][j+3] = v.w;
  }
  __syncthreads();
  u16* dst = Rt + (size_t)b * 16384;
  #pragma unroll
  for (int it = 0; it < 32; ++it){
    int idx = it*256 + tid;
    int j = idx >> 6, i2 = (idx & 63) * 2;
    unsigned lo = f2bf(sR[i2][j]), hi = f2bf(sR[i2+1][j]);
    *(unsigned*)&dst[j*128 + i2] = lo | (hi << 16);
  }
}

// ---------------- block-diagonal rotation, multi-tensor; optional fused silu(X)*X2 staging ----------------
__global__ __launch_bounds__(256) void rot_kernel(
    const u16* __restrict__ X, const u16* __restrict__ Rt,
    u16* __restrict__ Y0, u16* __restrict__ Y1, u16* __restrict__ Y2,
    int LD, int gpt, const u16* __restrict__ X2)
{
  __shared__ u16 sX[64][136];
  __shared__ u16 sRt[128][136];   // sRt[j][i]
  const int by = blockIdx.y, g = by % gpt;
  const int m0 = blockIdx.x * 64, tid = threadIdx.x;
  u16* Y = (by < gpt) ? Y0 : (by < 2*gpt ? Y1 : Y2);
  #pragma unroll
  for (int i = 0; i < 4; ++i){
    int vid = i*256 + tid, r = vid >> 4, c = (vid & 15) * 8;
    size_t gaddr = (size_t)(m0 + r) * LD + g*128 + c;
    short8 vx = *(const short8*)&X[gaddr];
    if (X2){
      short8 vu = *(const short8*)&X2[gaddr];
      const u16* px = (const u16*)&vx;
      const u16* pu = (const u16*)&vu;
      short8 o;
      u16* po = (u16*)&o;
      #pragma unroll
      for (int e = 0; e < 8; ++e){
        float gv = bf2f(px[e]), uv = bf2f(pu[e]);
        po[e] = f2bf(gv / (1.f + __expf(-gv)) * uv);
      }
      *(short8*)&sX[r][c] = o;
    } else {
      *(short8*)&sX[r][c] = vx;
    }
  }
  const u16* Rg = Rt + (size_t)by * 16384;
  #pragma unroll
  for (int it = 0; it < 8; ++it){
    int idx = it*256 + tid;
    int j = idx >> 4, c8 = (idx & 15) * 8;
    *(short8*)&sRt[j][c8] = *(const short8*)&Rg[j*128 + c8];
  }
  __syncthreads();
  const int lane = tid & 63, w = tid >> 6;
  const int fr = lane & 15, fq = lane >> 4, nw = w * 32;
  f32x4 acc[4][2];
  #pragma unroll
  for (int mi=0;mi<4;mi++)
    #pragma unroll
    for (int ni=0;ni<2;ni++) acc[mi][ni] = (f32x4){0.f,0.f,0.f,0.f};
  #pragma unroll
  for (int kk = 0; kk < 128; kk += 32){
    bf16x8 af[4], bv[2];
    #pragma unroll
    for (int mi=0;mi<4;mi++) af[mi] = ldb16(&sX[mi*16 + fr][kk + fq*8]);
    #pragma unroll
    for (int ni=0;ni<2;ni++) bv[ni] = ldb16(&sRt[nw + ni*16 + fr][kk + fq*8]);
    #pragma unroll
    for (int mi=0;mi<4;mi++)
      #pragma unroll
      for (int ni=0;ni<2;ni++)
        acc[mi][ni] = MFMA16(af[mi], bv[ni], acc[mi][ni]);
  }
  #pragma unroll
  for (int mi=0;mi<4;mi++)
    #pragma unroll
    for (int ni=0;ni<2;ni++)
      #pragma unroll
      for (int rg=0;rg<4;rg++){
        int m = m0 + mi*16 + fq*4 + rg;
        int n = g*128 + nw + ni*16 + fr;
        Y[(size_t)m * LD + n] = f2bf(acc[mi][ni][rg]);
      }
}

// ---------------- 256 x (NF*64) 8-wave GEMM, fused int4 dequant ----------------
// Depth-1.5 schedule (single rB set):
//   tile t: { ADMA(t+1) | half0 | vmcnt(4)->storeB (loadB(t+1) has >1 tile cover) |
//             half1 | loadB(t+2) | vmcnt(4NF) retires ADMA | lgkm0 | barrier }
template<int NF, bool PARTIAL, bool OUT_BF16>
__global__ __launch_bounds__(512, 1) void gemm_deq(
    const u16* __restrict__ A, const int* __restrict__ QW,
    const float* __restrict__ SC, void* __restrict__ Cout,
    int N, int K, int kc, int nN)
{
  __shared__ u16 sA[2][16384];        // [256][64] bf16, byte^=(row&7)<<4
  __shared__ u16 sB[2][NF * 4096];    // [NF*64][64] bf16, same swizzle
  const int tid = threadIdx.x;
  const int lane = tid & 63, w = tid >> 6;
  const int nblk = gridDim.x, q8 = nblk >> 3, b = blockIdx.x;
  const int l = (b & 7) * q8 + (b >> 3);
  const int mt = l & 3, rest = l >> 2;
  const int nt = rest % nN, z = rest / nN;
  const int bm0 = mt * 256, bn0 = nt * (NF * 64);
  const int kbase = z * kc;
  const int KG = K >> 7;
  const int nkt = kc >> 6;

  f32x4 acc[8][NF];
  #pragma unroll
  for (int i=0;i<8;i++)
    #pragma unroll
    for (int j=0;j<NF;j++) acc[i][j] = (f32x4){0.f,0.f,0.f,0.f};

  const int wr = (w >> 2) * 128, wc = (w & 3) * (NF * 16);
  const int fr = lane & 15, fq = lane >> 4;

  // ---- A DMA: wave w covers rows [w*32, w*32+32), 4 insts of 8 rows ----
  const int l8 = lane >> 3;
  const size_t K2 = (size_t)K * 2;
  const char* gA0 = (const char*)A
      + ((size_t)(bm0 + w*32 + l8) * K + (size_t)kbase) * 2
      + (((lane & 7) * 16) ^ (l8 << 4));
  auto ADMA = [&](int kt, int c){
    const char* g = gA0 + (size_t)kt * 128;
    char* lb = (char*)&sA[c][0] + (w*32) * 128;
    #pragma unroll
    for (int i=0;i<4;i++)
      gload_lds16(g + (size_t)(i*8) * K2, lb + i*1024);
  };

  // ---- B staging: thread covers rows (tid>>4)+32i (i<2*NF), int-cols (tid&15)*4 ----
  const int rBr = tid >> 4, cB4 = (tid & 15) * 4;
  const int* gB0 = QW + (size_t)(bn0 + rBr) * K + kbase + cB4;
  const float* gS0 = SC + (size_t)(bn0 + rBr) * KG;
  const int sBx = (cB4 * 2) ^ ((rBr & 7) << 4);   // (r&7) invariant under +32i

  int32x4 rB[2*NF];
  float   rS[2*NF];
  auto loadB = [&](int kt){
    const int* gb = gB0 + kt*64;
    const int g = (kbase + kt*64) >> 7;
    const float* ps = gS0 + g;
    #pragma unroll
    for (int i=0;i<2*NF;i++){
      rB[i] = *(const int32x4*)(gb + (size_t)i*32*K);
      rS[i] = ps[(size_t)i*32*KG];
    }
  };
  auto storeB = [&](int c){
    #pragma unroll
    for (int i=0;i<2*NF;i++){
      float s = rS[i], ns = -8.f * s;
      bf16x4 o;
      o[0] = (__bf16)fmaf((float)rB[i].x, s, ns);
      o[1] = (__bf16)fmaf((float)rB[i].y, s, ns);
      o[2] = (__bf16)fmaf((float)rB[i].z, s, ns);
      o[3] = (__bf16)fmaf((float)rB[i].w, s, ns);
      *(bf16x4*)((char*)&sB[c][0] + (rBr + 32*i)*128 + sBx) = o;
    }
  };

  auto mfma_half = [&](int c, int kk){
    bf16x8 af[8], bv[NF];
    #pragma unroll
    for (int mi=0;mi<8;mi++){
      int r = wr + mi*16 + fr;
      af[mi] = *(const bf16x8*)((const char*)&sA[c][0] + r*128 +
                ((kk*64 + fq*16) ^ ((r & 7) << 4)));
    }
    #pragma unroll
    for (int ni=0;ni<NF;ni++){
      int r = wc + ni*16 + fr;
      bv[ni] = *(const bf16x8*)((const char*)&sB[c][0] + r*128 +
                ((kk*64 + fq*16) ^ ((r & 7) << 4)));
    }
    __builtin_amdgcn_s_setprio(1);
    #pragma unroll
    for (int mi=0;mi<8;mi++)
      #pragma unroll
      for (int ni=0;ni<NF;ni++)
        acc[mi][ni] = MFMA16(af[mi], bv[ni], acc[mi][ni]);
    __builtin_amdgcn_s_setprio(0);
  };

#define WAIT_ADMA() do { if (NF==3) asm volatile("s_waitcnt vmcnt(12)" ::: "memory"); \
                         else       asm volatile("s_waitcnt vmcnt(16)" ::: "memory"); } while(0)

  // ---- prologue: stage tile 0 into buffers [0]; loadB(1) left in flight ----
  loadB(0);                 // 4*NF vmem
  ADMA(0, 0);               // 4 vmem
  asm volatile("s_waitcnt vmcnt(4)" ::: "memory");   // B(0)+scales retired
  __builtin_amdgcn_sched_barrier(0);
  storeB(0);
  if (nkt > 1){ loadB(1); __builtin_amdgcn_sched_barrier(0); }
  WAIT_ADMA();                                       // retire ADMA(0); loadB(1) stays
  asm volatile("s_waitcnt lgkmcnt(0)" ::: "memory");
  __builtin_amdgcn_s_barrier();

  int cb = 0;
  for (int t = 0; t < nkt; ++t){
    const bool more  = (t + 1) < nkt;
    const bool more2 = (t + 2) < nkt;
    if (more){
      ADMA(t+1, cb ^ 1);                 // sA[cb^1] free after the barrier
      __builtin_amdgcn_sched_barrier(0);
    }
    mfma_half(cb, 0);
    if (more){
      asm volatile("s_waitcnt vmcnt(4)" ::: "memory");  // loadB(t+1): >1 tile cover
      __builtin_amdgcn_sched_barrier(0);
      storeB(cb ^ 1);                    // dequant VALU overlaps other waves' MFMA
      __builtin_amdgcn_sched_barrier(0);
    }
    mfma_half(cb, 1);
    if (more){
      if (more2){
        loadB(t+2);                      // issue early; retires during next tile
        __builtin_amdgcn_sched_barrier(0);
        WAIT_ADMA();                     // retire ADMA(t+1); loadB(t+2) stays
      } else {
        asm volatile("s_waitcnt vmcnt(0)" ::: "memory");
      }
      asm volatile("s_waitcnt lgkmcnt(0)" ::: "memory");
      __builtin_amdgcn_sched_barrier(0);
      __builtin_amdgcn_s_barrier();
      cb ^= 1;
    }
  }
#undef WAIT_ADMA

  #pragma unroll
  for (int mi=0;mi<8;mi++)
    #pragma unroll
    for (int ni=0;ni<NF;ni++)
      #pragma unroll
      for (int rg=0;rg<4;rg++){
        size_t m = bm0 + wr + mi*16 + fq*4 + rg;
        size_t n = bn0 + wc + ni*16 + fr;
        float v = acc[mi][ni][rg];
        if (PARTIAL)          ((float*)Cout)[((size_t)z*1024 + m) * N + n] = v;
        else if (OUT_BF16)    ((u16*)Cout)[m * N + n] = f2bf(v);
        else                  ((float*)Cout)[m * N + n] = v;
      }
}

// ---------------- split-K reduce (f32x4), optional addend, f32 or bf16 out ----------------
__global__ __launch_bounds__(256) void reduce_splits(
    const float* __restrict__ P, int nsplit, int n,
    const float* __restrict__ addend, float* __restrict__ outf, u16* __restrict__ outb)
{
  size_t base = ((size_t)blockIdx.x*256 + threadIdx.x) * 4;
  if (base >= (size_t)n) return;
  f32x4 s = *(const f32x4*)&P[base];
  for (int j = 1; j < nsplit; ++j)
    s += *(const f32x4*)&P[(size_t)j*n + base];
  if (addend) s += *(const f32x4*)&addend[base];
  if (outb){
    short4v o;
    #pragma unroll
    for (int e=0;e<4;e++) o[e] = (short)f2bf(s[e]);
    *(short4v*)&outb[base] = o;
  } else {
    *(f32x4*)&outf[base] = s;
  }
}

// ---------------- fused split-K reduce + per-(t,head) RMSNorm over D=128 + RoPE ----------------
__global__ __launch_bounds__(64) void qknorm_rope_red(
    const float* __restrict__ P, int nsplit, int nh,
    const float* __restrict__ w, const int* __restrict__ pos, u16* __restrict__ out)
{
  const int t = blockIdx.x, h = blockIdx.y, j = threadIdx.x;
  const int N = nh * 128;
  const size_t stride = (size_t)T_ * N;
  const size_t base = (size_t)t * N + h*128;
  float x1 = 0.f, x2 = 0.f;
  for (int z = 0; z < nsplit; ++z){
    x1 += P[(size_t)z*stride + base + j];
    x2 += P[(size_t)z*stride + base + j + 64];
  }
  float ss = x1*x1 + x2*x2;
  #pragma unroll
  for (int off = 32; off; off >>= 1) ss += __shfl_xor(ss, off);
  float rn = rsqrtf(ss / 128.f + 1e-6f);
  float xn1 = x1 * rn * w[j], xn2 = x2 * rn * w[j + 64];
  float inv = exp2f(-(float)j * (19.93156856932417f / 64.f));
  float f = (float)pos[t] * inv;
  float sv, cv; sincosf(f, &sv, &cv);
  u16* orow = out + ((size_t)t * nh + h) * 128;
  orow[j]      = f2bf(xn1 * cv - xn2 * sv);
  orow[j + 64] = f2bf(xn2 * cv + xn1 * sv);
}

// ---------------- causal GQA flash attention, D=128, KV tiles of 32 ----------------
__global__ __launch_bounds__(256) void attn_kernel(
    const u16* __restrict__ Q, const u16* __restrict__ Kc,
    const u16* __restrict__ Vc, u16* __restrict__ O)
{
  __shared__ u16 sK[32][136];
  __shared__ u16 sVt[128][40];
  __shared__ u16 sP[4][16][40];
  const int b = blockIdx.x;
  const int qt = (b < 256) ? (b & 15) : (15 - (b & 15));
  const int h = b >> 4;
  const int kvh = h >> 2;
  const int tid = threadIdx.x, lane = tid & 63, w = tid >> 6;
  const int fr = lane & 15, fq = lane >> 4;
  const int r0 = qt*64 + w*16;
  const float scale = 0.08838834764831845f;
  bf16x8 aq[4];
  #pragma unroll
  for (int kd=0;kd<4;kd++)
    aq[kd] = ldb16(&Q[(size_t)(r0 + fr) * 4096 + h*128 + kd*32 + fq*8]);
  f32x4 accO[8];
  #pragma unroll
  for (int ni=0;ni<8;ni++) accO[ni] = (f32x4){0.f,0.f,0.f,0.f};
  float mrow[4] = {-1e30f,-1e30f,-1e30f,-1e30f};
  float lrow[4] = {0.f,0.f,0.f,0.f};
  const int ntiles = (qt + 1) * 2;
  for (int jt = 0; jt < ntiles; ++jt){
    __syncthreads();
    #pragma unroll
    for (int i=0;i<2;i++){
      int vid = i*256 + tid, r = vid >> 4, c = (vid & 15) * 8;
      *(short8*)&sK[r][c] = *(const short8*)&Kc[(size_t)(jt*32 + r) * 1024 + kvh*128 + c];
      short8 vv = *(const short8*)&Vc[(size_t)(jt*32 + r) * 1024 + kvh*128 + c];
      const u16* pv = (const u16*)&vv;
      #pragma unroll
      for (int e=0;e<8;e++) sVt[c + e][r] = pv[e];
    }
    __syncthreads();
    f32x4 accS[2]; accS[0] = (f32x4){0.f,0.f,0.f,0.f}; accS[1] = accS[0];
    #pragma unroll
    for (int kd=0;kd<4;kd++){
      #pragma unroll
      for (int ni=0;ni<2;ni++){
        bf16x8 bk = ldb16(&sK[ni*16 + fr][kd*32 + fq*8]);
        accS[ni] = MFMA16(aq[kd], bk, accS[ni]);
      }
    }
    float s[2][4];
    #pragma unroll
    for (int ni=0;ni<2;ni++)
      #pragma unroll
      for (int rg=0;rg<4;rg++){
        int row = r0 + fq*4 + rg, col = jt*32 + ni*16 + fr;
        float v = accS[ni][rg] * scale;
        s[ni][rg] = (col <= row) ? v : -1e30f;
      }
    float alpha[4];
    #pragma unroll
    for (int rg=0;rg<4;rg++){
      float mx = fmaxf(s[0][rg], s[1][rg]);
      #pragma unroll
      for (int off=1; off<16; off<<=1) mx = fmaxf(mx, __shfl_xor(mx, off, 16));
      float mnew = fmaxf(mrow[rg], mx);
      alpha[rg] = __expf(mrow[rg] - mnew);
      mrow[rg] = mnew;
      float p0 = __expf(s[0][rg] - mnew), p1 = __expf(s[1][rg] - mnew);
      s[0][rg] = p0; s[1][rg] = p1;
      float ps = p0 + p1;
      #pragma unroll
      for (int off=1; off<16; off<<=1) ps += __shfl_xor(ps, off, 16);
      lrow[rg] = lrow[rg] * alpha[rg] + ps;
    }
    #pragma unroll
    for (int ni=0;ni<2;ni++)
      #pragma unroll
      for (int rg=0;rg<4;rg++)
        sP[w][fq*4 + rg][ni*16 + fr] = f2bf(s[ni][rg]);
    __syncthreads();
    #pragma unroll
    for (int ni=0;ni<8;ni++)
      #pragma unroll
      for (int rg=0;rg<4;rg++) accO[ni][rg] *= alpha[rg];
    bf16x8 ap = ldb16(&sP[w][fr][fq*8]);
    #pragma unroll
    for (int ni=0;ni<8;ni++){
      bf16x8 bv = ldb16(&sVt[ni*16 + fr][fq*8]);
      accO[ni] = MFMA16(ap, bv, accO[ni]);
    }
  }
  #pragma unroll
  for (int ni=0;ni<8;ni++)
    #pragma unroll
    for (int rg=0;rg<4;rg++){
      int row = r0 + fq*4 + rg, col = h*128 + ni*16 + fr;
      O[(size_t)row * 4096 + col] = f2bf(accO[ni][rg] / lrow[rg]);
    }
}

extern "C" void kernel_launch(void* const* d_in, const int* in_sizes, int n_in,
                              void* d_out, int out_size, void* d_ws, size_t ws_size,
                              hipStream_t stream)
{
  const int*   positions = (const int*)  d_in[0];
  const float* hs    = (const float*)d_in[1];
  const float* resid = (const float*)d_in[2];
  const float* w_in  = (const float*)d_in[3];
  const float* w_post= (const float*)d_in[4];
  const float* w_qn  = (const float*)d_in[5];
  const float* w_kn  = (const float*)d_in[6];
  const float* R_q = (const float*)d_in[7];
  const int*   qw_q= (const int*)  d_in[8];
  const float* sc_q= (const float*)d_in[9];
  const float* R_k = (const float*)d_in[10];
  const int*   qw_k= (const int*)  d_in[11];
  const float* sc_k= (const float*)d_in[12];
  const float* R_v = (const float*)d_in[13];
  const int*   qw_v= (const int*)  d_in[14];
  const float* sc_v= (const float*)d_in[15];
  const float* R_o = (const float*)d_in[16];
  const int*   qw_o= (const int*)  d_in[17];
  const float* sc_o= (const float*)d_in[18];
  const float* R_g = (const float*)d_in[19];
  const int*   qw_g= (const int*)  d_in[20];
  const float* sc_g= (const float*)d_in[21];
  const float* R_u = (const float*)d_in[22];
  const int*   qw_u= (const int*)  d_in[23];
  const float* sc_u= (const float*)d_in[24];
  const float* R_d = (const float*)d_in[25];
  const int*   qw_d= (const int*)  d_in[26];
  const float* sc_d= (const float*)d_in[27];
  (void)in_sizes; (void)n_in; (void)out_size; (void)ws_size;

  char* wsp = (char*)d_ws; size_t off = 0;
  auto alloc = [&](size_t bytes)->void*{
    void* p = wsp + off; off += (bytes + 255) & ~(size_t)255; return p;
  };
  float* res  = (float*)alloc((size_t)T_*H_*4);       // 16MB
  u16*   xbf  = (u16*)  alloc((size_t)T_*H_*2);       // 8MB
  u16*   xrA  = (u16*)  alloc((size_t)T_*H_*2);       // 8MB
  u16*   xrB  = (u16*)  alloc((size_t)T_*H_*2);       // 8MB
  u16*   xrC  = (u16*)  alloc((size_t)T_*H_*2);       // 8MB
  float* qf   = (float*)alloc((size_t)T_*4096*4);     // 16MB (scratch, keeps layout)
  float* kf   = (float*)alloc((size_t)T_*1024*4);     // 4MB  (scratch)
  u16*   qbf  = (u16*)  alloc((size_t)T_*4096*2);     // 8MB
  u16*   kbf  = (u16*)  alloc((size_t)T_*1024*2);     // 2MB
  u16*   vbf  = (u16*)  alloc((size_t)T_*1024*2);     // 2MB
  u16*   abf  = (u16*)  alloc((size_t)T_*4096*2);     // 8MB
  u16*   gbf  = (u16*)  alloc((size_t)T_*I_*2);       // 24MB
  u16*   ubf  = (u16*)  alloc((size_t)T_*I_*2);       // 24MB
  u16*   hbf  = (u16*)  alloc((size_t)T_*I_*2);       // 24MB
  u16*   Rtb  = (u16*)  alloc((size_t)288*16384*2);   // 9.4MB precomputed R^T bf16
  (void)qf; (void)kf;

  // split-K partial regions reuse dead buffers (all sequential on one stream):
  float* pQKV = (float*)gbf;   // gbf..hbf (72MB) dead until gate-GEMM
  float* pO   = (float*)gbf;
  float* pD   = (float*)wsp;   // res..qf (64MB) dead at down-proj

  float* h2   = (float*)d_out;
  float* res2 = (float*)d_out + (size_t)T_*H_;

  rprep_kernel<<<288, 256, 0, stream>>>(R_q, R_k, R_v, R_o, R_g, R_u, R_d, Rtb);
  addnorm_kernel<<<T_, 256, 0, stream>>>(hs, resid, w_in, res, xbf);
  // QKV rotations in one launch (share xbf)
  rot_kernel<<<dim3(16,96),256,0,stream>>>(xbf, Rtb, xrA, xrB, xrC, H_, 32, nullptr);
  // q: N=4096 (nN=16), z=4 (kc=1024) -> 256 blocks; fused reduce+norm+rope
  gemm_deq<4,true ,false><<<256,512,0,stream>>>(xrA, qw_q, sc_q, pQKV, 4096, 4096, 1024, 16);
  qknorm_rope_red<<<dim3(T_,NH_ ),64,0,stream>>>(pQKV, 4, NH_, w_qn, positions, qbf);
  // k: N=1024 (nN=4), z=16 (kc=256) -> 256 blocks; fused reduce+norm+rope
  gemm_deq<4,true ,false><<<256,512,0,stream>>>(xrB, qw_k, sc_k, pQKV, 1024, 4096, 256, 4);
  qknorm_rope_red<<<dim3(T_,NKV_),64,0,stream>>>(pQKV, 16, NKV_, w_kn, positions, kbf);
  // v: N=1024, z=16 -> 256 blocks, bf16 out via reduce
  gemm_deq<4,true ,false><<<256,512,0,stream>>>(xrC, qw_v, sc_v, pQKV, 1024, 4096, 256, 4);
  reduce_splits<<<(T_*1024)/1024,256,0,stream>>>(pQKV, 16, T_*1024, nullptr, nullptr, vbf);
  attn_kernel<<<512,256,0,stream>>>(qbf, kbf, vbf, abf);
  rot_kernel<<<dim3(16,32),256,0,stream>>>(abf, Rtb + (size_t)96*16384, xrA, nullptr, nullptr, H_, 32, nullptr);
  // o: z=4 -> 256 blocks; fused reduce + residual + post-norm
  gemm_deq<4,true ,false><<<256,512,0,stream>>>(xrA, qw_o, sc_o, pO, 4096, 4096, 1024, 16);
  addnorm_red_kernel<<<T_,256,0,stream>>>(pO, 4, res, w_post, res2, xbf);
  // gate/up rotations in one launch
  rot_kernel<<<dim3(16,64),256,0,stream>>>(xbf, Rtb + (size_t)128*16384, xrA, xrB, nullptr, H_, 32, nullptr);
  // gate: NF=3 (BN=192), nN=64 -> 256 blocks, z=1, direct bf16 out
  gemm_deq<3,false,true ><<<256,512,0,stream>>>(xrA, qw_g, sc_g, gbf, 12288, 4096, 4096, 64);
  // up: same, plain
  gemm_deq<3,false,true ><<<256,512,0,stream>>>(xrB, qw_u, sc_u, ubf, 12288, 4096, 4096, 64);
  // down-rot with fused silu(gate)*up staging: reads gbf+ubf, writes rotated hbf
  rot_kernel<<<dim3(16,96),256,0,stream>>>(gbf, Rtb + (size_t)192*16384, hbf, nullptr, nullptr, I_, 96, ubf);
  // down: N=4096 (nN=16), K=12288, z=4 (kc=3072) -> 256 blocks
  gemm_deq<4,true ,false><<<256,512,0,stream>>>(hbf, qw_d, sc_d, pD, 4096, 12288, 3072, 16);
  reduce_splits<<<(T_*4096)/1024,256,0,stream>>>(pD, 4, T_*4096, nullptr, h2, nullptr);
}